// Round 7
// baseline (4636.145 us; speedup 1.0000x reference)
//
#include <hip/hip_runtime.h>

#define NPTS 131072
#define DIM 64          // floats per row = 16 float4 chunks
#define KC 1024
#define BLK 256
#define MT 64           // points per block
#define NT 128          // clusters per pass
#define NPASS (KC / NT) // 8
#define DC 16           // float4 chunks per row
#define XPAD (MT + 1)   // padded LDS row stride (float4 units)
#define EPAD (NT + 1)

// ---------------- kernel A: embedding row norms ----------------
__global__ void enorm_kernel(const float* __restrict__ emb, float* __restrict__ enorm) {
    int k = blockIdx.x * blockDim.x + threadIdx.x;
    if (k < KC) {
        const float4* e = (const float4*)(emb + (size_t)k * DIM);
        float s = 0.f;
#pragma unroll
        for (int j = 0; j < DC; ++j) {
            float4 v = e[j];
            s += v.x * v.x + v.y * v.y + v.z * v.z + v.w * v.w;
        }
        enorm[k] = s;
    }
}

// ---------------- kernel B: register-tiled distance GEMM + argmin + scatter ----------------
// 4 waves in 2x2: wm = point half (32 pts), wn = cluster half (64 clusters).
// Each lane: 4 points x 8 clusters outer product. acc[4][8]=32 VGPR -> no spill.
__global__ __launch_bounds__(BLK, 3) void assign_kernel(
    const float* __restrict__ x, const float* __restrict__ emb,
    const float* __restrict__ enorm,
    float* __restrict__ count, float* __restrict__ weight,
    double* __restrict__ dacc)
{
    __shared__ float4 xT[DC * XPAD];   // [dc][p], padded: 16.6 KB
    __shared__ float4 eT[DC * EPAD];   // [dc][c], padded: 33 KB
    __shared__ float  bvL[2][MT];
    __shared__ int    bcL[2][MT];
    __shared__ float  xnL[MT];
    __shared__ float  wsum[4];

    const int tid  = threadIdx.x;
    const int lane = tid & 63;
    const int wid  = tid >> 6;      // 0..3
    const int wm   = wid >> 1;      // point half (0/1)
    const int wn   = wid & 1;       // cluster half (0/1)
    const int kc   = lane & 7;      // cluster-group lane coord (0..7)
    const int pr   = lane >> 3;     // point-group lane coord (0..7)
    const size_t pblock = (size_t)blockIdx.x * MT;

    // ---- stage xT: global [p][dc] (coalesced) -> LDS [dc][p] (padded row -> <=2-way write conflict)
    {
        const float4* xg = (const float4*)(x + pblock * DIM);
#pragma unroll
        for (int s = 0; s < (DC * MT) / BLK; ++s) {   // 4 per thread
            int g = s * BLK + tid;
            int p = g >> 4, dc = g & 15;
            xT[dc * XPAD + p] = xg[g];
        }
    }

    float bv[4], xn[4];
    int   bc[4];
#pragma unroll
    for (int i = 0; i < 4; ++i) { bv[i] = 3.4e38f; bc[i] = 0; xn[i] = 0.f; }

    for (int pass = 0; pass < NPASS; ++pass) {
        __syncthreads();   // prev pass done with eT (pass0: xT staged)
        const float4* eg = (const float4*)(emb + (size_t)pass * NT * DIM);
#pragma unroll
        for (int s = 0; s < (DC * NT) / BLK; ++s) {   // 8 per thread
            int g = s * BLK + tid;
            int c = g >> 4, dc = g & 15;
            eT[dc * EPAD + c] = eg[g];
        }
        __syncthreads();

        float eNr[8];
#pragma unroll
        for (int j = 0; j < 8; ++j) eNr[j] = enorm[pass * NT + wn * 64 + 8 * j + kc];

        float acc[4][8];
#pragma unroll
        for (int i = 0; i < 4; ++i)
#pragma unroll
            for (int j = 0; j < 8; ++j) acc[i][j] = 0.f;

#pragma unroll
        for (int dc = 0; dc < DC; ++dc) {
            float4 a[4], b[8];
#pragma unroll
            for (int j = 0; j < 8; ++j) b[j] = eT[dc * EPAD + wn * 64 + 8 * j + kc];
#pragma unroll
            for (int i = 0; i < 4; ++i) a[i] = xT[dc * XPAD + wm * 32 + 8 * i + pr];
#pragma unroll
            for (int i = 0; i < 4; ++i)
#pragma unroll
                for (int j = 0; j < 8; ++j) {
                    acc[i][j] = fmaf(a[i].x, b[j].x, acc[i][j]);
                    acc[i][j] = fmaf(a[i].y, b[j].y, acc[i][j]);
                    acc[i][j] = fmaf(a[i].z, b[j].z, acc[i][j]);
                    acc[i][j] = fmaf(a[i].w, b[j].w, acc[i][j]);
                }
            if (pass == 0) {
#pragma unroll
                for (int i = 0; i < 4; ++i) {
                    xn[i] = fmaf(a[i].x, a[i].x, xn[i]);
                    xn[i] = fmaf(a[i].y, a[i].y, xn[i]);
                    xn[i] = fmaf(a[i].z, a[i].z, xn[i]);
                    xn[i] = fmaf(a[i].w, a[i].w, xn[i]);
                }
            }
        }

        const int cbase = pass * NT + wn * 64 + kc;
#pragma unroll
        for (int i = 0; i < 4; ++i)
#pragma unroll
            for (int j = 0; j < 8; ++j) {
                float s = fmaf(-2.f, acc[i][j], eNr[j]);
                int   c = cbase + 8 * j;
                if (s < bv[i] || (s == bv[i] && c < bc[i])) { bv[i] = s; bc[i] = c; }
            }
    }

    // ---- cross-kc reduce: 8 lanes (same pr, kc=0..7) hold the same 4 points
#pragma unroll
    for (int i = 0; i < 4; ++i) {
#pragma unroll
        for (int m = 1; m < 8; m <<= 1) {
            float ov = __shfl_xor(bv[i], m, 64);
            int   oc = __shfl_xor(bc[i], m, 64);
            if (ov < bv[i] || (ov == bv[i] && oc < bc[i])) { bv[i] = ov; bc[i] = oc; }
        }
    }

    if (kc == 0) {
#pragma unroll
        for (int i = 0; i < 4; ++i) {
            int p = wm * 32 + 8 * i + pr;
            bvL[wn][p] = bv[i];
            bcL[wn][p] = bc[i];
            if (wn == 0) xnL[p] = xn[i];
        }
    }
    __syncthreads();

    // ---- combine wave halves, distortion, scatter (4 threads / point)
    const int p  = tid >> 2;     // 0..63
    const int hf = tid & 3;      // dc quarter
    float bvp = bvL[0][p];
    int   bcp = bcL[0][p];
    {
        float ov = bvL[1][p];
        int   oc = bcL[1][p];
        if (ov < bvp || (ov == bvp && oc < bcp)) { bvp = ov; bcp = oc; }
    }
    float dloc = (hf == 0) ? (xnL[p] + bvp) : 0.f;

#pragma unroll
    for (int off = 32; off; off >>= 1) dloc += __shfl_down(dloc, off, 64);
    if (lane == 0) wsum[wid] = dloc;
    __syncthreads();
    if (tid == 0) atomicAdd(dacc, (double)(wsum[0] + wsum[1] + wsum[2] + wsum[3]));

    if (hf == 0) unsafeAtomicAdd(&count[bcp], 1.0f);
    float* w = weight + (size_t)bcp * DIM + hf * 16;
#pragma unroll
    for (int q = 0; q < 4; ++q) {
        float4 v = xT[(hf * 4 + q) * XPAD + p];
        unsafeAtomicAdd(&w[4 * q + 0], v.x);
        unsafeAtomicAdd(&w[4 * q + 1], v.y);
        unsafeAtomicAdd(&w[4 * q + 2], v.z);
        unsafeAtomicAdd(&w[4 * q + 3], v.w);
    }
}

// ---------------- kernel C: finalize -> d_out ----------------
__global__ void finalize_kernel(const float* __restrict__ count,
                                const float* __restrict__ weight,
                                const double* __restrict__ dacc,
                                float* __restrict__ out)
{
    int idx = blockIdx.x * BLK + threadIdx.x;
    const float denomf = (float)(131072.0 + (double)KC * 1.0e-5);  // n + K*eps
    if (idx < KC * DIM) {
        int k = idx >> 6;
        float cn = (count[k] + 1e-5f) / denomf * 131072.0f;
        out[1 + idx] = weight[idx] / cn;
    } else if (idx < KC * DIM + KC) {
        int k = idx - KC * DIM;
        float cn = (count[k] + 1e-5f) / denomf * 131072.0f;
        out[1 + KC * DIM + k] = cn;
    } else if (idx == KC * DIM + KC) {
        out[0] = (float)(*dacc * (1.0 / ((double)NPTS * (double)DIM)));
    }
}

extern "C" void kernel_launch(void* const* d_in, const int* in_sizes, int n_in,
                              void* d_out, int out_size, void* d_ws, size_t ws_size,
                              hipStream_t stream)
{
    // inputs: [0]=it (int scalar, unused), [1]=x_flat f32 [N,D], [2]=embedding f32 [K,D]
    const float* x   = (const float*)d_in[1];
    const float* emb = (const float*)d_in[2];
    float* out = (float*)d_out;

    // ws layout: enorm[K] | count[K] | weight[K*D] | dacc (double, 8B-aligned)
    float*  enorm  = (float*)d_ws;
    float*  count  = enorm + KC;
    float*  weight = count + KC;
    size_t  daccOff = (size_t)(2 * KC + KC * DIM) * sizeof(float);  // 270336 B
    double* dacc   = (double*)((char*)d_ws + daccOff);

    hipMemsetAsync(d_ws, 0, daccOff + sizeof(double), stream);

    enorm_kernel<<<(KC + BLK - 1) / BLK, BLK, 0, stream>>>(emb, enorm);
    assign_kernel<<<NPTS / MT, BLK, 0, stream>>>(x, emb, enorm, count, weight, dacc);

    int fin_elems = KC * DIM + KC + 1;
    finalize_kernel<<<(fin_elems + BLK - 1) / BLK, BLK, 0, stream>>>(count, weight, dacc, out);
}

// Round 16
// 2175.828 us; speedup vs baseline: 2.1307x; 2.1307x over previous
//
#include <hip/hip_runtime.h>

#define NPTS 131072
#define DIM 64          // floats per row = 16 float4 chunks
#define KC 1024
#define BLK 256
#define MT 64           // points per block
#define NT 128          // clusters per pass
#define NPASS (KC / NT) // 8
#define DC 16           // float4 chunks per row
#define XPAD (MT + 1)   // padded LDS row stride (float4 units)
#define EPAD (NT + 1)

// ---------------- kernel A: embedding row norms ----------------
__global__ void enorm_kernel(const float* __restrict__ emb, float* __restrict__ enorm) {
    int k = blockIdx.x * blockDim.x + threadIdx.x;
    if (k < KC) {
        const float4* e = (const float4*)(emb + (size_t)k * DIM);
        float s = 0.f;
#pragma unroll
        for (int j = 0; j < DC; ++j) {
            float4 v = e[j];
            s += v.x * v.x + v.y * v.y + v.z * v.z + v.w * v.w;
        }
        enorm[k] = s;
    }
}

// ---------------- kernel B: register-tiled distance GEMM + argmin + scatter ----------------
// 4 waves in 2x2: wm = point half (32 pts), wn = cluster half (64 clusters).
// Each lane: 4 points x 8 clusters outer product. acc[4][8]=32 VGPR.
// NOTE: no second __launch_bounds__ arg — round 7 showed (256,3) forces VGPR=84
// and spills acc to scratch (17 GB HBM traffic). Default 256-reg cap fits the
// ~150-reg live set with slack.
__global__ __launch_bounds__(BLK) void assign_kernel(
    const float* __restrict__ x, const float* __restrict__ emb,
    const float* __restrict__ enorm,
    float* __restrict__ count, float* __restrict__ weight,
    double* __restrict__ dacc)
{
    __shared__ float4 xT[DC * XPAD];   // [dc][p], padded: 16.6 KB
    __shared__ float4 eT[DC * EPAD];   // [dc][c], padded: 33 KB
    __shared__ float  bvL[2][MT];
    __shared__ int    bcL[2][MT];
    __shared__ float  xnL[MT];
    __shared__ float  wsum[4];

    const int tid  = threadIdx.x;
    const int lane = tid & 63;
    const int wid  = tid >> 6;      // 0..3
    const int wm   = wid >> 1;      // point half (0/1)
    const int wn   = wid & 1;       // cluster half (0/1)
    const int kc   = lane & 7;      // cluster-group lane coord (0..7)
    const int pr   = lane >> 3;     // point-group lane coord (0..7)
    const size_t pblock = (size_t)blockIdx.x * MT;

    // ---- stage xT: global [p][dc] (coalesced) -> LDS [dc][p] (padded row)
    {
        const float4* xg = (const float4*)(x + pblock * DIM);
#pragma unroll
        for (int s = 0; s < (DC * MT) / BLK; ++s) {   // 4 per thread
            int g = s * BLK + tid;
            int p = g >> 4, dc = g & 15;
            xT[dc * XPAD + p] = xg[g];
        }
    }

    float bv[4], xn[4];
    int   bc[4];
#pragma unroll
    for (int i = 0; i < 4; ++i) { bv[i] = 3.4e38f; bc[i] = 0; xn[i] = 0.f; }

    for (int pass = 0; pass < NPASS; ++pass) {
        __syncthreads();   // prev pass done with eT (pass0: xT staged)
        const float4* eg = (const float4*)(emb + (size_t)pass * NT * DIM);
#pragma unroll
        for (int s = 0; s < (DC * NT) / BLK; ++s) {   // 8 per thread
            int g = s * BLK + tid;
            int c = g >> 4, dc = g & 15;
            eT[dc * EPAD + c] = eg[g];
        }
        __syncthreads();

        float eNr[8];
#pragma unroll
        for (int j = 0; j < 8; ++j) eNr[j] = enorm[pass * NT + wn * 64 + 8 * j + kc];

        float acc[4][8];
#pragma unroll
        for (int i = 0; i < 4; ++i)
#pragma unroll
            for (int j = 0; j < 8; ++j) acc[i][j] = 0.f;

#pragma unroll
        for (int dc = 0; dc < DC; ++dc) {
            float4 a[4], b[8];
#pragma unroll
            for (int j = 0; j < 8; ++j) b[j] = eT[dc * EPAD + wn * 64 + 8 * j + kc];
#pragma unroll
            for (int i = 0; i < 4; ++i) a[i] = xT[dc * XPAD + wm * 32 + 8 * i + pr];
#pragma unroll
            for (int i = 0; i < 4; ++i)
#pragma unroll
                for (int j = 0; j < 8; ++j) {
                    acc[i][j] = fmaf(a[i].x, b[j].x, acc[i][j]);
                    acc[i][j] = fmaf(a[i].y, b[j].y, acc[i][j]);
                    acc[i][j] = fmaf(a[i].z, b[j].z, acc[i][j]);
                    acc[i][j] = fmaf(a[i].w, b[j].w, acc[i][j]);
                }
            if (pass == 0) {
#pragma unroll
                for (int i = 0; i < 4; ++i) {
                    xn[i] = fmaf(a[i].x, a[i].x, xn[i]);
                    xn[i] = fmaf(a[i].y, a[i].y, xn[i]);
                    xn[i] = fmaf(a[i].z, a[i].z, xn[i]);
                    xn[i] = fmaf(a[i].w, a[i].w, xn[i]);
                }
            }
        }

        const int cbase = pass * NT + wn * 64 + kc;
#pragma unroll
        for (int i = 0; i < 4; ++i)
#pragma unroll
            for (int j = 0; j < 8; ++j) {
                float s = fmaf(-2.f, acc[i][j], eNr[j]);
                int   c = cbase + 8 * j;
                if (s < bv[i] || (s == bv[i] && c < bc[i])) { bv[i] = s; bc[i] = c; }
            }
    }

    // ---- cross-kc reduce: 8 lanes (same pr, kc=0..7) hold the same 4 points
#pragma unroll
    for (int i = 0; i < 4; ++i) {
#pragma unroll
        for (int m = 1; m < 8; m <<= 1) {
            float ov = __shfl_xor(bv[i], m, 64);
            int   oc = __shfl_xor(bc[i], m, 64);
            if (ov < bv[i] || (ov == bv[i] && oc < bc[i])) { bv[i] = ov; bc[i] = oc; }
        }
    }

    if (kc == 0) {
#pragma unroll
        for (int i = 0; i < 4; ++i) {
            int p = wm * 32 + 8 * i + pr;
            bvL[wn][p] = bv[i];
            bcL[wn][p] = bc[i];
            if (wn == 0) xnL[p] = xn[i];
        }
    }
    __syncthreads();

    // ---- combine wave halves, distortion, scatter (4 threads / point)
    const int p  = tid >> 2;     // 0..63
    const int hf = tid & 3;      // dc quarter
    float bvp = bvL[0][p];
    int   bcp = bcL[0][p];
    {
        float ov = bvL[1][p];
        int   oc = bcL[1][p];
        if (ov < bvp || (ov == bvp && oc < bcp)) { bvp = ov; bcp = oc; }
    }
    float dloc = (hf == 0) ? (xnL[p] + bvp) : 0.f;

#pragma unroll
    for (int off = 32; off; off >>= 1) dloc += __shfl_down(dloc, off, 64);
    if (lane == 0) wsum[wid] = dloc;
    __syncthreads();
    if (tid == 0) atomicAdd(dacc, (double)(wsum[0] + wsum[1] + wsum[2] + wsum[3]));

    if (hf == 0) unsafeAtomicAdd(&count[bcp], 1.0f);
    float* w = weight + (size_t)bcp * DIM + hf * 16;
#pragma unroll
    for (int q = 0; q < 4; ++q) {
        float4 v = xT[(hf * 4 + q) * XPAD + p];
        unsafeAtomicAdd(&w[4 * q + 0], v.x);
        unsafeAtomicAdd(&w[4 * q + 1], v.y);
        unsafeAtomicAdd(&w[4 * q + 2], v.z);
        unsafeAtomicAdd(&w[4 * q + 3], v.w);
    }
}

// ---------------- kernel C: finalize -> d_out ----------------
__global__ void finalize_kernel(const float* __restrict__ count,
                                const float* __restrict__ weight,
                                const double* __restrict__ dacc,
                                float* __restrict__ out)
{
    int idx = blockIdx.x * BLK + threadIdx.x;
    const float denomf = (float)(131072.0 + (double)KC * 1.0e-5);  // n + K*eps
    if (idx < KC * DIM) {
        int k = idx >> 6;
        float cn = (count[k] + 1e-5f) / denomf * 131072.0f;
        out[1 + idx] = weight[idx] / cn;
    } else if (idx < KC * DIM + KC) {
        int k = idx - KC * DIM;
        float cn = (count[k] + 1e-5f) / denomf * 131072.0f;
        out[1 + KC * DIM + k] = cn;
    } else if (idx == KC * DIM + KC) {
        out[0] = (float)(*dacc * (1.0 / ((double)NPTS * (double)DIM)));
    }
}

extern "C" void kernel_launch(void* const* d_in, const int* in_sizes, int n_in,
                              void* d_out, int out_size, void* d_ws, size_t ws_size,
                              hipStream_t stream)
{
    // inputs: [0]=it (int scalar, unused), [1]=x_flat f32 [N,D], [2]=embedding f32 [K,D]
    const float* x   = (const float*)d_in[1];
    const float* emb = (const float*)d_in[2];
    float* out = (float*)d_out;

    // ws layout: enorm[K] | count[K] | weight[K*D] | dacc (double, 8B-aligned)
    float*  enorm  = (float*)d_ws;
    float*  count  = enorm + KC;
    float*  weight = count + KC;
    size_t  daccOff = (size_t)(2 * KC + KC * DIM) * sizeof(float);  // 270336 B
    double* dacc   = (double*)((char*)d_ws + daccOff);

    hipMemsetAsync(d_ws, 0, daccOff + sizeof(double), stream);

    enorm_kernel<<<(KC + BLK - 1) / BLK, BLK, 0, stream>>>(emb, enorm);
    assign_kernel<<<NPTS / MT, BLK, 0, stream>>>(x, emb, enorm, count, weight, dacc);

    int fin_elems = KC * DIM + KC + 1;
    finalize_kernel<<<(fin_elems + BLK - 1) / BLK, BLK, 0, stream>>>(count, weight, dacc, out);
}